// Round 5
// baseline (106.207 us; speedup 1.0000x reference)
//
#include <hip/hip_runtime.h>
#include <hip/hip_fp16.h>

// GEMM view: Out[(b,d), c] = sum_k A[(b,d),k] * Bk[k,c]
//   row = b*32 + d (M=131072), k = i*32+j (K=1024), col = c (N=64)
// A[(b,d), i*32+j] = x[b,i,d] * y[b,j,d]  — rank-1 in (i,j), built in regs.
// R7: single-kernel, no workspace. B is reg-staged straight from raw kern
// (m173 pattern: pre-swizzled per-thread global address + linear LDS dest):
//   thread (wave,lane) owns c = wave*16+n16, jb = quad*8; per chunk ci it
//   loads rows i = ci*4+r (r=0..3), 8 contiguous f32 = 2 dwordx4 each,
//   RNE-converts to f16 (same numerics as the old kswz pre-pass) and
//   ds_write_b128's into the same fragment layout the DMA produced.
// x streamed per-chunk via global_load_lds (raw f32, dup'd in-loop).
// Pipeline: 9 vmem ops/chunk (8 B + 1 x); counted s_waitcnt vmcnt(9)
// (vmcnt(0) only at the tail), raw s_barrier, issue chunk p+2 in phase p.
// 2-slot B ring (32 KB) + 3-slot x ring (12 KB) = 44 KB LDS, 2 blocks/CU.
// 512 blocks x 256 thr, 8 b/block, wave = 2 b x full C. T5 setprio on MFMA.

typedef __attribute__((ext_vector_type(8))) _Float16 half8;   // MFMA operand
typedef __attribute__((ext_vector_type(2))) __fp16 fp16x2;    // cvt_pkrtz/pk_mul
typedef __attribute__((ext_vector_type(4))) float f32x4;
typedef __attribute__((ext_vector_type(8))) short short8;

__device__ __forceinline__ unsigned int dup_h(float f) {
    union { fp16x2 h; unsigned int u; } w;
    w.h = __builtin_amdgcn_cvt_pkrtz(f, f);
    return w.u;
}
__device__ __forceinline__ fp16x2 pk2(float a, float b) {
    return __builtin_amdgcn_cvt_pkrtz(a, b);
}
__device__ __forceinline__ void gld_lds16(const void* g, void* l) {
    __builtin_amdgcn_global_load_lds(
        (const __attribute__((address_space(1))) unsigned int*)g,
        (__attribute__((address_space(3))) unsigned int*)l, 16, 0, 0);
}

__global__ __launch_bounds__(256, 2) void cin_main(const float* __restrict__ x,
                                                   const float* __restrict__ y,
                                                   const float* __restrict__ kern,
                                                   float* __restrict__ out_mat,
                                                   float* __restrict__ out_fin) {
    __shared__ __align__(16) unsigned short kb[2][8192];  // 32 KB: B ring (16 KB/chunk)
    __shared__ __align__(16) float xb[3][1024];           // 12 KB: x ring (4 KB/chunk)

    const int tid  = threadIdx.x;
    const int wave = tid >> 6;        // 0..3
    const int lane = tid & 63;
    const int quad = lane >> 4;
    const int n16  = lane & 15;
    const int b_blk = blockIdx.x * 8;
    const int cq0   = blockIdx.x & 7;

    // x-DMA source decomposition: elem idx = tid*4 = xbb*128 + xii*32 + xd4*4
    const int xbb = tid >> 5, xii = (tid >> 3) & 3, xd4 = tid & 7;

    // B staging: this thread covers c = wave*16+n16, j = quad*8..+7; per chunk
    // ci the 4 groups are rows i = ci*4+r. Dest elem off = r*2048 + tid*8
    // == group g_loc*8 with g_loc = r*256+tid — identical layout to old DMA.
    const float* bsrc = kern + (size_t)(wave * 16 + n16) * 1024 + quad * 8;

    float4 breg[2][8];  // two in-flight chunks of B (compile-time indexed only)

    auto issue_B = [&](int ci, int par) {
        const float* s0 = bsrc + ci * 128;
#pragma unroll
        for (int r = 0; r < 4; ++r) {
            breg[par][2 * r]     = *(const float4*)(s0 + r * 32);
            breg[par][2 * r + 1] = *(const float4*)(s0 + r * 32 + 4);
        }
    };
    auto issue_x = [&](int ci, int slot) {
        gld_lds16(x + (size_t)(b_blk + xbb) * 1024 + ci * 128 + xii * 32 + xd4 * 4,
                  &xb[slot][wave * 256]);
    };
    auto write_B = [&](int par, int slot) {
#pragma unroll
        for (int r = 0; r < 4; ++r) {
            union { half8 h; short8 s; } v;
#pragma unroll
            for (int t = 0; t < 4; ++t) {
                v.h[t]     = (_Float16)breg[par][2 * r][t];      // RNE, == kswz
                v.h[4 + t] = (_Float16)breg[par][2 * r + 1][t];
            }
            *(short8*)(&kb[slot][r * 2048 + tid * 8]) = v.s;
        }
    };

    // ---- prologue: chunks cq0, cq0+1 in flight ----
    issue_B(cq0, 0);           issue_x(cq0, 0);
    issue_B((cq0 + 1) & 7, 1); issue_x((cq0 + 1) & 7, 1);

    // ---- y fragments: yv2[mt][p] = {y[b,j=q8+2p,d], y[b,j=q8+2p+1,d]} ----
    const int b0 = b_blk + wave * 2;  // wave owns b0..b0+1
    fp16x2 yv2[4][4];
#pragma unroll
    for (int mt = 0; mt < 4; ++mt) {
        const int b = b0 + (mt >> 1);
        const int d = n16 + 16 * (mt & 1);
        const float* yp = y + (size_t)b * 1024 + (quad * 8) * 32 + d;
#pragma unroll
        for (int p = 0; p < 4; ++p)
            yv2[mt][p] = pk2(yp[(2 * p) * 32], yp[(2 * p + 1) * 32]);
    }

    f32x4 acc[4][4];
#pragma unroll
    for (int mt = 0; mt < 4; ++mt)
#pragma unroll
        for (int nt = 0; nt < 4; ++nt) acc[mt][nt] = (f32x4){0.f, 0.f, 0.f, 0.f};

    // chunk cq0 -> kb[0] (compiler inserts the vmcnt wait for breg[0])
    write_B(0, 0);
    asm volatile("s_waitcnt lgkmcnt(0)" ::: "memory");
    __builtin_amdgcn_s_barrier();
    __builtin_amdgcn_sched_barrier(0);

#pragma unroll
    for (int p = 0; p < 8; ++p) {
        // issue chunk p+2 (9 vmem ops) into breg[p&1] / xb[(p+2)%3];
        // slot (p+2)%3 was fully read in phase p-1 (barrier-published).
        if (p <= 5) { issue_B((cq0 + p + 2) & 7, p & 1); issue_x((cq0 + p + 2) & 7, (p + 2) % 3); }
        // retire chunk p+1's 9 ops: outstanding drops to the 9 just issued.
        if (p <= 5)      asm volatile("s_waitcnt vmcnt(9)" ::: "memory");
        else if (p == 6) asm volatile("s_waitcnt vmcnt(0)" ::: "memory");
        // convert+write chunk p+1 into the slot freed by the opening barrier
        if (p <= 6) write_B((p + 1) & 1, (p + 1) & 1);

        const unsigned short* kbase = &kb[p & 1][0];
        const float*          xbase = &xb[p % 3][0];

        __builtin_amdgcn_s_setprio(1);
#pragma unroll
        for (int k = 0; k < 4; ++k) {
            half8 bf[4];
#pragma unroll
            for (int nt = 0; nt < 4; ++nt)
                bf[nt] = *(const half8*)(kbase + ((k * 4 + nt) * 64 + lane) * 8);
#pragma unroll
            for (int mt = 0; mt < 4; ++mt) {
                float xf = xbase[(wave * 2 + (mt >> 1)) * 128 + k * 32 + n16 + 16 * (mt & 1)];
                union { unsigned int u; fp16x2 h; } xv;
                xv.u = dup_h(xf);
                union { half8 h8; fp16x2 h2[4]; } af;
#pragma unroll
                for (int pq = 0; pq < 4; ++pq) af.h2[pq] = xv.h * yv2[mt][pq];  // v_pk_mul_f16
#pragma unroll
                for (int nt = 0; nt < 4; ++nt)
                    acc[mt][nt] = __builtin_amdgcn_mfma_f32_16x16x32_f16(
                        af.h8, bf[nt], acc[mt][nt], 0, 0, 0);
            }
        }
        __builtin_amdgcn_s_setprio(0);

        asm volatile("s_waitcnt lgkmcnt(0)" ::: "memory");
        __builtin_amdgcn_s_barrier();
        __builtin_amdgcn_sched_barrier(0);
    }

    // ---- epilogue: output_mat[b][c][d], d = 16*(mt&1) + quad*4 + t ----
#pragma unroll
    for (int mt = 0; mt < 4; ++mt) {
        const int b = b0 + (mt >> 1);
        const int dbase = 16 * (mt & 1) + quad * 4;
#pragma unroll
        for (int nt = 0; nt < 4; ++nt) {
            const int c = nt * 16 + n16;
            *(f32x4*)(out_mat + (size_t)b * 2048 + c * 32 + dbase) = acc[mt][nt];
        }
    }

    // ---- final_output[b][c] = sum_d output_mat[b][c][d] ----
#pragma unroll
    for (int a = 0; a < 2; ++a) {
        const int b = b0 + a;
#pragma unroll
        for (int nt = 0; nt < 4; ++nt) {
            float f = 0.f;
#pragma unroll
            for (int t = 0; t < 4; ++t) f += acc[2 * a][nt][t] + acc[2 * a + 1][nt][t];
            f += __shfl_xor(f, 16);
            f += __shfl_xor(f, 32);
            if (lane < 16) out_fin[(size_t)b * 64 + nt * 16 + n16] = f;
        }
    }
}

extern "C" void kernel_launch(void* const* d_in, const int* in_sizes, int n_in,
                              void* d_out, int out_size, void* d_ws, size_t ws_size,
                              hipStream_t stream) {
    const float* x    = (const float*)d_in[0];   // [4096,32,32]
    const float* y    = (const float*)d_in[1];   // [4096,32,32]
    const float* kern = (const float*)d_in[2];   // [64,32,32]
    float* out_mat = (float*)d_out;                      // [4096,64,32]
    float* out_fin = (float*)d_out + 4096 * 64 * 32;     // [4096,64]
    (void)d_ws; (void)ws_size;                           // workspace unused

    cin_main<<<512, 256, 0, stream>>>(x, y, kern, out_mat, out_fin);
}

// Round 6
// 104.087 us; speedup vs baseline: 1.0204x; 1.0204x over previous
//
#include <hip/hip_runtime.h>
#include <hip/hip_fp16.h>

// GEMM view: Out[(b,d), c] = sum_k A[(b,d),k] * Bk[k,c]
//   row = b*32 + d (M=131072), k = i*32+j (K=1024), col = c (N=64)
// A[(b,d), i*32+j] = x[b,i,d] * y[b,j,d]  — rank-1 in (i,j), built in regs.
// R8 = R6 structure (kswz pre-pass + global_load_lds + counted vmcnt), with
// grid-level write-tail pipelining: 1024 blocks x 4 b (2 dispatch rounds at
// 2 blocks/CU) so round-2 compute overlaps round-1's store drain.
//  - wave = 2 b x half-C: chalf = wave&1 (c 0-31 / 32-63), bp = wave>>1.
//  - B: 3-slot ring (48 KB), 4 gld_lds16/chunk, chunk p+2 issued in phase p.
//  - x: pair-chunks (4 KB = 2 k-chunks), 2-slot ring (8 KB), 1 gld_lds16/wave
//    issued at even phases; cq0 = (blockIdx&3)*2 keeps pairs mod-8-aligned.
//  - static wait table (FIFO-derived, 9 ops per 2 phases):
//    p0:vmcnt(4) [retire B(c0)+X(p0), leave B(c1)] ; odd p:vmcnt(5) [retire
//    B-only batch] ; even p:vmcnt(4) [retire B+X batch] ; p7:vmcnt(0).
//  - T5 setprio around MFMA cluster. LDS 56 KB, 2 blocks/CU.

typedef __attribute__((ext_vector_type(8))) _Float16 half8;   // MFMA operand
typedef __attribute__((ext_vector_type(2))) __fp16 fp16x2;    // cvt_pkrtz/pk_mul
typedef __attribute__((ext_vector_type(4))) float f32x4;
typedef __attribute__((ext_vector_type(8))) short short8;

__device__ __forceinline__ unsigned int dup_h(float f) {
    union { fp16x2 h; unsigned int u; } w;
    w.h = __builtin_amdgcn_cvt_pkrtz(f, f);
    return w.u;
}
__device__ __forceinline__ fp16x2 pk2(float a, float b) {
    return __builtin_amdgcn_cvt_pkrtz(a, b);
}
__device__ __forceinline__ void gld_lds16(const void* g, void* l) {
    __builtin_amdgcn_global_load_lds(
        (const __attribute__((address_space(1))) unsigned int*)g,
        (__attribute__((address_space(3))) unsigned int*)l, 16, 0, 0);
}

// kswz f16 frag order: g = (s*4+nt)*64 + lane,
// kswz[g*8+t] = f16(kernel[c = nt*16+(lane&15)][s][(lane>>4)*8 + t])
__global__ __launch_bounds__(256) void kswz_kernel(const float* __restrict__ kern,
                                                   unsigned short* __restrict__ kswz) {
    int idx  = blockIdx.x * 256 + threadIdx.x;  // 8192
    int lane = idx & 63;
    int nt   = (idx >> 6) & 3;
    int s    = idx >> 8;
    int c    = nt * 16 + (lane & 15);
    int jb   = (lane >> 4) * 8;
    const float* src = kern + c * 1024 + s * 32 + jb;
    union { half8 h; short8 s8; } v;
#pragma unroll
    for (int t = 0; t < 8; ++t) v.h[t] = (_Float16)src[t];  // RNE
    *(short8*)(kswz + (size_t)idx * 8) = v.s8;
}

__global__ __launch_bounds__(256, 2) void cin_main(const float* __restrict__ x,
                                                   const float* __restrict__ y,
                                                   const unsigned short* __restrict__ kswz,
                                                   float* __restrict__ out_mat,
                                                   float* __restrict__ out_fin) {
    __shared__ __align__(16) unsigned short kb[3][8192];  // 48 KB: B ring (16 KB/chunk)
    __shared__ __align__(16) float xb[2][1024];           // 8 KB: x pair ring (4 KB/pair)

    const int tid   = threadIdx.x;
    const int wave  = tid >> 6;        // 0..3
    const int lane  = tid & 63;
    const int quad  = lane >> 4;
    const int n16   = lane & 15;
    const int chalf = wave & 1;        // c-half: c in [chalf*32, chalf*32+32)
    const int bp    = wave >> 1;       // b-pair within block
    const int b_blk = blockIdx.x * 4;
    const int cq0   = (blockIdx.x & 3) * 2;   // even -> x pairs stay mod-8 aligned

    // ---- B chunk DMA: 4 calls x 256 thr x 16 B = 16 KB ----
    auto issue_B = [&](int ci, int slot) {
#pragma unroll
        for (int r = 0; r < 4; ++r)
            gld_lds16(kswz + (size_t)ci * 8192 + (r * 256 + tid) * 8,
                      &kb[slot][r * 2048 + wave * 512]);
    };
    // ---- x pair DMA: wave w covers b = b_blk+w, 8 rows, 32 d = 1 KB ----
    // lane l: i_loc = l>>3 (0..7), d4 = (l&7)*4; LDS idx = w*256 + l*4.
    auto issue_X = [&](int P, int slot) {
        const int rowbase = ((cq0 + 2 * P) & 7) * 4;  // aligned: rows contiguous
        gld_lds16(x + (size_t)(b_blk + wave) * 1024 + (rowbase + (lane >> 3)) * 32 + (lane & 7) * 4,
                  &xb[slot][wave * 256]);
    };

    // ---- prologue (order matters for FIFO wait math): B(c0), X(pair0), B(c1)
    issue_B(cq0, 0);
    issue_X(0, 0);
    issue_B((cq0 + 1) & 7, 1);

    // ---- y fragments: yv2[mt][p] = {y[b,j=q8+2p,d], y[b,j=q8+2p+1,d]} ----
    const int b0 = b_blk + bp * 2;  // wave's b-pair
    fp16x2 yv2[4][4];
#pragma unroll
    for (int mt = 0; mt < 4; ++mt) {
        const int b = b0 + (mt >> 1);
        const int d = n16 + 16 * (mt & 1);
        const float* yp = y + (size_t)b * 1024 + (quad * 8) * 32 + d;
#pragma unroll
        for (int p = 0; p < 4; ++p)
            yv2[mt][p] = pk2(yp[(2 * p) * 32], yp[(2 * p + 1) * 32]);
    }

    f32x4 acc[4][2];
#pragma unroll
    for (int mt = 0; mt < 4; ++mt)
#pragma unroll
        for (int nt = 0; nt < 2; ++nt) acc[mt][nt] = (f32x4){0.f, 0.f, 0.f, 0.f};

#pragma unroll
    for (int p = 0; p < 8; ++p) {
        // static FIFO-derived waits (see header comment)
        if (p == 7)       asm volatile("s_waitcnt vmcnt(0)" ::: "memory");
        else if (p & 1)   asm volatile("s_waitcnt vmcnt(5)" ::: "memory");
        else              asm volatile("s_waitcnt vmcnt(4)" ::: "memory");
        __builtin_amdgcn_s_barrier();
        __builtin_amdgcn_sched_barrier(0);   // rule 18: no hoist above the wait

        // issues AFTER the barrier (the barrier frees the target slots)
        if (p <= 5) issue_B((cq0 + p + 2) & 7, (p + 2) % 3);
        if (p <= 4 && (p & 1) == 0) issue_X(p / 2 + 1, (p / 2 + 1) & 1);

        const unsigned short* kbase = &kb[p % 3][0];
        const float*          xbase = &xb[(p / 2) & 1][0];

        __builtin_amdgcn_s_setprio(1);
#pragma unroll
        for (int k = 0; k < 4; ++k) {
            half8 bf[2];
#pragma unroll
            for (int nt = 0; nt < 2; ++nt)
                bf[nt] = *(const half8*)(kbase + ((k * 4 + chalf * 2 + nt) * 64 + lane) * 8);
#pragma unroll
            for (int mt = 0; mt < 4; ++mt) {
                // x row within pair region: i_loc = (p&1)*4 + k
                float xf = xbase[(bp * 2 + (mt >> 1)) * 256 + ((p & 1) * 4 + k) * 32 +
                                 n16 + 16 * (mt & 1)];
                union { unsigned int u; fp16x2 h; } xv;
                xv.u = dup_h(xf);
                union { half8 h8; fp16x2 h2[4]; } af;
#pragma unroll
                for (int pq = 0; pq < 4; ++pq) af.h2[pq] = xv.h * yv2[mt][pq];  // v_pk_mul_f16
#pragma unroll
                for (int nt = 0; nt < 2; ++nt)
                    acc[mt][nt] = __builtin_amdgcn_mfma_f32_16x16x32_f16(
                        af.h8, bf[nt], acc[mt][nt], 0, 0, 0);
            }
        }
        __builtin_amdgcn_s_setprio(0);
    }

    // ---- epilogue: output_mat[b][c][d], d = 16*(mt&1) + quad*4 + t ----
#pragma unroll
    for (int mt = 0; mt < 4; ++mt) {
        const int b = b0 + (mt >> 1);
        const int dbase = 16 * (mt & 1) + quad * 4;
#pragma unroll
        for (int nt = 0; nt < 2; ++nt) {
            const int c = chalf * 32 + nt * 16 + n16;
            *(f32x4*)(out_mat + (size_t)b * 2048 + c * 32 + dbase) = acc[mt][nt];
        }
    }

    // ---- final_output[b][c] = sum_d output_mat[b][c][d] ----
#pragma unroll
    for (int a = 0; a < 2; ++a) {
        const int b = b0 + a;
#pragma unroll
        for (int nt = 0; nt < 2; ++nt) {
            float f = 0.f;
#pragma unroll
            for (int t = 0; t < 4; ++t) f += acc[2 * a][nt][t] + acc[2 * a + 1][nt][t];
            f += __shfl_xor(f, 16);
            f += __shfl_xor(f, 32);
            if (lane < 16) out_fin[(size_t)b * 64 + chalf * 32 + nt * 16 + n16] = f;
        }
    }
}

extern "C" void kernel_launch(void* const* d_in, const int* in_sizes, int n_in,
                              void* d_out, int out_size, void* d_ws, size_t ws_size,
                              hipStream_t stream) {
    const float* x    = (const float*)d_in[0];   // [4096,32,32]
    const float* y    = (const float*)d_in[1];   // [4096,32,32]
    const float* kern = (const float*)d_in[2];   // [64,32,32]
    float* out_mat = (float*)d_out;                      // [4096,64,32]
    float* out_fin = (float*)d_out + 4096 * 64 * 32;     // [4096,64]
    unsigned short* kswz = (unsigned short*)d_ws;        // 65536 f16 = 128 KB

    kswz_kernel<<<32, 256, 0, stream>>>(kern, kswz);
    cin_main<<<1024, 256, 0, stream>>>(x, y, kswz, out_mat, out_fin);
}

// Round 7
// 100.652 us; speedup vs baseline: 1.0552x; 1.0341x over previous
//
#include <hip/hip_runtime.h>
#include <hip/hip_fp16.h>

// GEMM view: Out[(b,d), c] = sum_k A[(b,d),k] * Bk[k,c]
//   row = b*32 + d (M=131072), k = i*32+j (K=1024), col = c (N=64)
// A[(b,d), i*32+j] = x[b,i,d] * y[b,j,d]  — rank-1 in (i,j), built in regs.
// R9 = exact revert to R6 (best measured: 100.69 µs total; cin_main ~12.7 µs
// vs ~10.6 µs composite floor). R7 (raw-kern staging, no ws) and R8 (1024-blk
// grid split) both regressed — kswz pre-pass + 512 blocks x full-C waves is
// the verified optimum of this structure.
//  - x streamed per-chunk via global_load_lds (raw f32, dup'd in-loop).
//  - 3-slot LDS ring {B 16KB + x 4KB}/chunk = 60 KB total, 2 blocks/CU.
//  - counted s_waitcnt vmcnt(5) (vmcnt(0) only on last chunk) + raw
//    s_barrier + sched_barrier(0); chunk i+2 issued AFTER the barrier.
//  - T5 setprio(1) around the MFMA cluster.
// 512 blocks x 256 thr, 8 b/block, wave = 2 b x full C.

typedef __attribute__((ext_vector_type(8))) _Float16 half8;   // MFMA operand
typedef __attribute__((ext_vector_type(2))) __fp16 fp16x2;    // cvt_pkrtz/pk_mul
typedef __attribute__((ext_vector_type(4))) float f32x4;
typedef __attribute__((ext_vector_type(8))) short short8;

__device__ __forceinline__ unsigned int dup_h(float f) {
    union { fp16x2 h; unsigned int u; } w;
    w.h = __builtin_amdgcn_cvt_pkrtz(f, f);
    return w.u;
}
__device__ __forceinline__ fp16x2 pk2(float a, float b) {
    return __builtin_amdgcn_cvt_pkrtz(a, b);
}

// kswz f16 frag order: g = (s*4+nt)*64 + lane,
// kswz[g*8+t] = f16(kernel[c = nt*16+(lane&15)][s][(lane>>4)*8 + t])
__global__ __launch_bounds__(256) void kswz_kernel(const float* __restrict__ kern,
                                                   unsigned short* __restrict__ kswz) {
    int idx  = blockIdx.x * 256 + threadIdx.x;  // 8192
    int lane = idx & 63;
    int nt   = (idx >> 6) & 3;
    int s    = idx >> 8;
    int c    = nt * 16 + (lane & 15);
    int jb   = (lane >> 4) * 8;
    const float* src = kern + c * 1024 + s * 32 + jb;
    union { half8 h; short8 s8; } v;
#pragma unroll
    for (int t = 0; t < 8; ++t) v.h[t] = (_Float16)src[t];  // RNE
    *(short8*)(kswz + (size_t)idx * 8) = v.s8;
}

__device__ __forceinline__ void gld_lds16(const void* g, void* l) {
    __builtin_amdgcn_global_load_lds(
        (const __attribute__((address_space(1))) unsigned int*)g,
        (__attribute__((address_space(3))) unsigned int*)l, 16, 0, 0);
}

__global__ __launch_bounds__(256, 2) void cin_main(const float* __restrict__ x,
                                                   const float* __restrict__ y,
                                                   const unsigned short* __restrict__ kswz,
                                                   float* __restrict__ out_mat,
                                                   float* __restrict__ out_fin) {
    __shared__ __align__(16) unsigned short kb[3][8192];  // 48 KB: B ring (16 KB/chunk)
    __shared__ __align__(16) float xb[3][1024];           // 12 KB: x ring (4 KB/chunk)

    const int tid  = threadIdx.x;
    const int wave = tid >> 6;        // 0..3
    const int lane = tid & 63;
    const int quad = lane >> 4;
    const int n16  = lane & 15;
    const int b_blk = blockIdx.x * 8;
    const int cq0   = blockIdx.x & 7;

    // per-thread x-DMA source decomposition: elem idx = tid*4 = bb*128+ii*32+d4*4
    const int xbb = tid >> 5;         // b within block 0..7
    const int xii = (tid >> 3) & 3;   // i within chunk 0..3
    const int xd4 = tid & 7;          // float4 within row

    // ---- issue one chunk's DMA: B 4 calls + x 1 call per thread ----
    auto issue_chunk = [&](int ci, int slot) {
#pragma unroll
        for (int r = 0; r < 4; ++r)
            gld_lds16(kswz + (size_t)ci * 8192 + (r * 256 + tid) * 8,
                      &kb[slot][r * 2048 + wave * 512]);
        gld_lds16(x + (size_t)(b_blk + xbb) * 1024 + ci * 128 + xii * 32 + xd4 * 4,
                  &xb[slot][wave * 256]);
    };

    // prologue: chunks cq0, cq0+1 into slots 0,1 (DMA runs under the y-load)
    issue_chunk(cq0, 0);
    issue_chunk((cq0 + 1) & 7, 1);

    // ---- y fragments as packed pairs: yv2[mt][p] = {y[b,j=q8+2p,d], y[b,j=q8+2p+1,d]} ----
    const int b0 = b_blk + wave * 2;  // wave owns b0..b0+1
    fp16x2 yv2[4][4];
#pragma unroll
    for (int mt = 0; mt < 4; ++mt) {
        const int b = b0 + (mt >> 1);
        const int d = n16 + 16 * (mt & 1);
        const float* yp = y + (size_t)b * 1024 + (quad * 8) * 32 + d;
#pragma unroll
        for (int p = 0; p < 4; ++p)
            yv2[mt][p] = pk2(yp[(2 * p) * 32], yp[(2 * p + 1) * 32]);
    }

    f32x4 acc[4][4];
#pragma unroll
    for (int mt = 0; mt < 4; ++mt)
#pragma unroll
        for (int nt = 0; nt < 4; ++nt) acc[mt][nt] = (f32x4){0.f, 0.f, 0.f, 0.f};

#pragma unroll
    for (int p8 = 0; p8 < 8; ++p8) {
        // chunk p8 ready = this wave's own 5 calls retired (all but the last 5
        // outstanding are retired -> everything through chunk p8 landed);
        // barrier makes all 4 waves' segments visible AND frees slot (p8-1)%3.
        if (p8 < 7) asm volatile("s_waitcnt vmcnt(5)" ::: "memory");
        else        asm volatile("s_waitcnt vmcnt(0)" ::: "memory");
        __builtin_amdgcn_s_barrier();
        __builtin_amdgcn_sched_barrier(0);   // rule 18: no hoist above the wait

        if (p8 < 6) issue_chunk((cq0 + p8 + 2) & 7, (p8 + 2) % 3);

        const unsigned short* kbase = &kb[p8 % 3][0];
        const float*          xbase = &xb[p8 % 3][0];

        __builtin_amdgcn_s_setprio(1);
#pragma unroll
        for (int k = 0; k < 4; ++k) {
            half8 bf[4];
#pragma unroll
            for (int nt = 0; nt < 4; ++nt)
                bf[nt] = *(const half8*)(kbase + ((k * 4 + nt) * 64 + lane) * 8);
#pragma unroll
            for (int mt = 0; mt < 4; ++mt) {
                float xf = xbase[(wave * 2 + (mt >> 1)) * 128 + k * 32 + n16 + 16 * (mt & 1)];
                union { unsigned int u; fp16x2 h; } xv;
                xv.u = dup_h(xf);
                union { half8 h8; fp16x2 h2[4]; } af;
#pragma unroll
                for (int p = 0; p < 4; ++p) af.h2[p] = xv.h * yv2[mt][p];  // v_pk_mul_f16
#pragma unroll
                for (int nt = 0; nt < 4; ++nt)
                    acc[mt][nt] = __builtin_amdgcn_mfma_f32_16x16x32_f16(
                        af.h8, bf[nt], acc[mt][nt], 0, 0, 0);
            }
        }
        __builtin_amdgcn_s_setprio(0);
    }

    // ---- epilogue: output_mat[b][c][d], d = 16*(mt&1) + quad*4 + t ----
#pragma unroll
    for (int mt = 0; mt < 4; ++mt) {
        const int b = b0 + (mt >> 1);
        const int dbase = 16 * (mt & 1) + quad * 4;
#pragma unroll
        for (int nt = 0; nt < 4; ++nt) {
            const int c = nt * 16 + n16;
            *(f32x4*)(out_mat + (size_t)b * 2048 + c * 32 + dbase) = acc[mt][nt];
        }
    }

    // ---- final_output[b][c] = sum_d output_mat[b][c][d] ----
#pragma unroll
    for (int a = 0; a < 2; ++a) {
        const int b = b0 + a;
#pragma unroll
        for (int nt = 0; nt < 4; ++nt) {
            float f = 0.f;
#pragma unroll
            for (int t = 0; t < 4; ++t) f += acc[2 * a][nt][t] + acc[2 * a + 1][nt][t];
            f += __shfl_xor(f, 16);
            f += __shfl_xor(f, 32);
            if (lane < 16) out_fin[(size_t)b * 64 + nt * 16 + n16] = f;
        }
    }
}

extern "C" void kernel_launch(void* const* d_in, const int* in_sizes, int n_in,
                              void* d_out, int out_size, void* d_ws, size_t ws_size,
                              hipStream_t stream) {
    const float* x    = (const float*)d_in[0];   // [4096,32,32]
    const float* y    = (const float*)d_in[1];   // [4096,32,32]
    const float* kern = (const float*)d_in[2];   // [64,32,32]
    float* out_mat = (float*)d_out;                      // [4096,64,32]
    float* out_fin = (float*)d_out + 4096 * 64 * 32;     // [4096,64]
    unsigned short* kswz = (unsigned short*)d_ws;        // 65536 f16 = 128 KB

    kswz_kernel<<<32, 256, 0, stream>>>(kern, kswz);
    cin_main<<<512, 256, 0, stream>>>(x, y, kswz, out_mat, out_fin);
}